// Round 6
// baseline (217.890 us; speedup 1.0000x reference)
//
#include <hip/hip_runtime.h>

#define B_ 2
#define N_ 2048
#define H_ 1024
#define NH_ 16
#define D_ 64

typedef _Float16 f16;
typedef _Float16 f16x4 __attribute__((ext_vector_type(4)));
typedef _Float16 f16x8 __attribute__((ext_vector_type(8)));
typedef float f32x4 __attribute__((ext_vector_type(4)));

#define MFMA16(a, b, c) __builtin_amdgcn_mfma_f32_16x16x32_f16((a), (b), (c), 0, 0, 0)
#define MFMA16K(a, b, c) __builtin_amdgcn_mfma_f32_16x16x16f16((a), (b), (c), 0, 0, 0)

// async global->LDS, 16B per lane; lds dest = base + lane*16 (wave-uniform base)
__device__ __forceinline__ void cp16(void* lds, const void* g) {
  __builtin_amdgcn_global_load_lds(
      (const __attribute__((address_space(1))) void*)g,
      (__attribute__((address_space(3))) void*)lds, 16, 0, 0);
}

// ---------------------------------------------------------------------------
// fp32 -> f16 convert (x, x2), 8 elems/thread
// ---------------------------------------------------------------------------
__global__ __launch_bounds__(256) void convf16(
    const float* __restrict__ a, const float* __restrict__ b,
    f16* __restrict__ ao, f16* __restrict__ bo) {
  const size_t i = ((size_t)blockIdx.x * 256 + threadIdx.x) * 8;
  const float* __restrict__ src = (blockIdx.y == 0) ? a : b;
  f16* __restrict__ dst = (blockIdx.y == 0) ? ao : bo;
  float4 v0 = ((const float4*)(src + i))[0];
  float4 v1 = ((const float4*)(src + i))[1];
  f16x8 o;
  o[0] = (f16)v0.x; o[1] = (f16)v0.y; o[2] = (f16)v0.z; o[3] = (f16)v0.w;
  o[4] = (f16)v1.x; o[5] = (f16)v1.y; o[6] = (f16)v1.z; o[7] = (f16)v1.w;
  *(f16x8*)(dst + i) = o;
}

// ---------------------------------------------------------------------------
// Transpose+convert: W f32 [rows][ncols] -> Wt f16 [ncols][rows]
// ---------------------------------------------------------------------------
__global__ __launch_bounds__(256) void transw(
    const float* __restrict__ W, f16* __restrict__ Wt, int rows, int ncols) {
  const int cb = blockIdx.x * 64, kb = blockIdx.y * 64;
  const int t = threadIdx.x;
  __shared__ f16 T[64][72];
  {
    const int k = t >> 2, c0 = (t & 3) * 16;
    const float* wp = W + (size_t)(kb + k) * ncols + cb + c0;
    float4 w0 = ((const float4*)wp)[0];
    float4 w1 = ((const float4*)wp)[1];
    float4 w2 = ((const float4*)wp)[2];
    float4 w3 = ((const float4*)wp)[3];
    T[c0 + 0][k] = (f16)w0.x;  T[c0 + 1][k] = (f16)w0.y;
    T[c0 + 2][k] = (f16)w0.z;  T[c0 + 3][k] = (f16)w0.w;
    T[c0 + 4][k] = (f16)w1.x;  T[c0 + 5][k] = (f16)w1.y;
    T[c0 + 6][k] = (f16)w1.z;  T[c0 + 7][k] = (f16)w1.w;
    T[c0 + 8][k] = (f16)w2.x;  T[c0 + 9][k] = (f16)w2.y;
    T[c0 + 10][k] = (f16)w2.z; T[c0 + 11][k] = (f16)w2.w;
    T[c0 + 12][k] = (f16)w3.x; T[c0 + 13][k] = (f16)w3.y;
    T[c0 + 14][k] = (f16)w3.z; T[c0 + 15][k] = (f16)w3.w;
  }
  __syncthreads();
  {
    const int c = t >> 2, k0 = (t & 3) * 16;
    f16* op = Wt + (size_t)(cb + c) * rows + kb + k0;
    *(f16x8*)(op + 0) = *(const f16x8*)(&T[c][k0]);
    *(f16x8*)(op + 8) = *(const f16x8*)(&T[c][k0 + 8]);
  }
}

// ---------------------------------------------------------------------------
// Transpose V: f16 [bh][N][D] -> Vt f16 [bh][D][N]
// ---------------------------------------------------------------------------
__global__ __launch_bounds__(256) void transv(
    const f16* __restrict__ V, f16* __restrict__ Vt) {
  const int nb = blockIdx.x * 64, bh = blockIdx.y;
  const int t = threadIdx.x;
  __shared__ f16 T[64][72];
  {
    const int n = t >> 2, d0 = (t & 3) * 16;
    const f16* vp = V + ((size_t)bh * N_ + nb + n) * D_ + d0;
    f16x8 v0 = *(const f16x8*)(vp);
    f16x8 v1 = *(const f16x8*)(vp + 8);
#pragma unroll
    for (int i = 0; i < 8; ++i) T[d0 + i][n] = v0[i];
#pragma unroll
    for (int i = 0; i < 8; ++i) T[d0 + 8 + i][n] = v1[i];
  }
  __syncthreads();
  {
    const int d = t >> 2, n0 = (t & 3) * 16;
    f16* op = Vt + ((size_t)bh * D_ + d) * N_ + nb + n0;
    *(f16x8*)(op + 0) = *(const f16x8*)(&T[d][n0]);
    *(f16x8*)(op + 8) = *(const f16x8*)(&T[d][n0 + 8]);
  }
}

// ---------------------------------------------------------------------------
// QKV GEMM, m97-style: C[4096,3072] = A_f16 @ WqkvT_f16^T.
// ---------------------------------------------------------------------------
__global__ __launch_bounds__(256) void qkv_mfma(
    const f16* __restrict__ Xc, const f16* __restrict__ X2c,
    const f16* __restrict__ Wt, f16* __restrict__ Qo,
    f16* __restrict__ Ko, f16* __restrict__ Vo) {
  const int bid = blockIdx.x;
  const int rb = (bid & 31) * 128;
  const int cb = (bid >> 5) * 128;
  const int t = threadIdx.x;
  const int lane = t & 63, wid = t >> 6;
  const int quad = lane >> 4, n16 = lane & 15;
  const int wm = wid >> 1, wn = wid & 1;

  const f16* __restrict__ A = (cb < H_) ? Xc : X2c;
  const int seg = cb >> 10;
  const float qscale = (seg == 0) ? 0.125f * 1.44269504f : 1.0f;
  f16* __restrict__ outp = (seg == 0) ? Qo : (seg == 1 ? Ko : Vo);

  __shared__ f16 As[128 * 32];
  __shared__ f16 Bs[128 * 32];

  f32x4 acc[4][4];
#pragma unroll
  for (int i = 0; i < 4; ++i)
#pragma unroll
    for (int j = 0; j < 4; ++j) acc[i][j] = (f32x4){0.f, 0.f, 0.f, 0.f};

  int srow0 = wid * 16 + (lane >> 2);
  int srow1 = 64 + srow0;
  int gl0 = ((lane & 3) ^ ((srow0 >> 1) & 3)) * 8;
  int gl1 = ((lane & 3) ^ ((srow1 >> 1) & 3)) * 8;
  const f16* gA0 = A + (size_t)(rb + srow0) * H_ + gl0;
  const f16* gA1 = A + (size_t)(rb + srow1) * H_ + gl1;
  const f16* gB0 = Wt + (size_t)(cb + srow0) * H_ + gl0;
  const f16* gB1 = Wt + (size_t)(cb + srow1) * H_ + gl1;
  f16* lA0 = &As[wid * 512];
  f16* lA1 = &As[2048 + wid * 512];
  f16* lB0 = &Bs[wid * 512];
  f16* lB1 = &Bs[2048 + wid * 512];

  const int fsw = (quad ^ ((n16 >> 1) & 3)) * 8;
  int aoff[4], boff[4];
#pragma unroll
  for (int i = 0; i < 4; ++i) {
    aoff[i] = (wm * 64 + i * 16 + n16) * 32 + fsw;
    boff[i] = (wn * 64 + i * 16 + n16) * 32 + fsw;
  }

  for (int kt = 0; kt < H_; kt += 32) {
    __syncthreads();
    cp16(lA0, gA0); cp16(lA1, gA1);
    cp16(lB0, gB0); cp16(lB1, gB1);
    gA0 += 32; gA1 += 32; gB0 += 32; gB1 += 32;
    __syncthreads();

    f16x8 af[4], bf[4];
#pragma unroll
    for (int mt = 0; mt < 4; ++mt) af[mt] = *(const f16x8*)(&As[aoff[mt]]);
#pragma unroll
    for (int nt = 0; nt < 4; ++nt) bf[nt] = *(const f16x8*)(&Bs[boff[nt]]);
#pragma unroll
    for (int mt = 0; mt < 4; ++mt)
#pragma unroll
      for (int nt = 0; nt < 4; ++nt)
        acc[mt][nt] = MFMA16(af[mt], bf[nt], acc[mt][nt]);
  }

#pragma unroll
  for (int mt = 0; mt < 4; ++mt)
#pragma unroll
    for (int nt = 0; nt < 4; ++nt)
#pragma unroll
      for (int r = 0; r < 4; ++r) {
        int grow = rb + wm * 64 + mt * 16 + quad * 4 + r;
        int gcol = cb + wn * 64 + nt * 16 + n16;
        int bb = grow >> 11, nn = grow & 2047;
        int hh = (gcol >> 6) & 15, dd = gcol & 63;
        outp[(((size_t)(bb * NH_ + hh)) * N_ + nn) * D_ + dd] =
            (f16)(acc[mt][nt][r] * qscale);
      }
}

// ---------------------------------------------------------------------------
// Flash attention v4: key-split waves for 2x arithmetic intensity per LDS byte.
// Block: 64 queries x 128-key tiles, 4 waves. Wave = (qh = wid&1, kh = wid>>1):
// 32 queries (2 chunks of 16) x its own 64-key half. K-frags (8 b128) and
// V-frags (16 b64) are query-independent -> amortized over 2 q-chunks.
// P stays in registers (S^T C-layout == PV K16 A-layout). Key-half partial O
// and lsum combined once at the end via LDS reduction (Ks region reused).
// ---------------------------------------------------------------------------
__global__ __launch_bounds__(256) void attn4(
    const f16* __restrict__ Q, const f16* __restrict__ K,
    const f16* __restrict__ Vt, f16* __restrict__ AO) {
  const int bh = blockIdx.y;
  const int b = bh >> 4, h = bh & 15;
  const int qb = blockIdx.x * 64;
  const int t = threadIdx.x;
  const int lane = t & 63, wid = t >> 6;
  const int quad = lane >> 4, n16 = lane & 15;
  const int qh = wid & 1;   // query half
  const int kh = wid >> 1;  // key half

  const f16* __restrict__ Qp = Q + (size_t)bh * N_ * D_;
  const f16* __restrict__ Kp = K + (size_t)bh * N_ * D_;
  const f16* __restrict__ Vp = Vt + (size_t)bh * D_ * N_;  // [d][n]

  __shared__ f16 Ks[2][64 * 64];  // [kh][key][d], XOR-8 granule swizzle
  __shared__ f16 Vs[2][64 * 64];  // [kh][d][key], XOR-8 granule swizzle

  // Q B-frags: 2 chunks of 16 queries (rows qb + qh*32 + qc*16 + n16)
  f16x8 qf[2][2];
#pragma unroll
  for (int qc = 0; qc < 2; ++qc) {
    const f16* qp = Qp + (size_t)(qb + qh * 32 + qc * 16 + n16) * D_ + quad * 8;
    qf[qc][0] = *(const f16x8*)(qp);
    qf[qc][1] = *(const f16x8*)(qp + 32);
  }

  f32x4 o[2][4];
#pragma unroll
  for (int i = 0; i < 2; ++i)
#pragma unroll
    for (int j = 0; j < 4; ++j) o[i][j] = (f32x4){0.f, 0.f, 0.f, 0.f};
  float lsum[2] = {0.f, 0.f};

  // staging: per region, issue j covers rows j*32 + wid*8 + lane/8, granule lane&7
  const int srow0 = wid * 8 + (lane >> 3);
  const int srow1 = 32 + srow0;
  const int gl0 = ((lane & 7) ^ (srow0 & 7)) * 8;
  const int gl1 = ((lane & 7) ^ (srow1 & 7)) * 8;
  const f16* gK0 = Kp + (size_t)srow0 * D_ + gl0;
  const f16* gK1 = Kp + (size_t)srow1 * D_ + gl1;
  const f16* gV0 = Vp + (size_t)srow0 * N_ + gl0;
  const f16* gV1 = Vp + (size_t)srow1 * N_ + gl1;

  // fragment offsets
  const int fs0 = (quad ^ (n16 & 7)) * 8;
  const int fs1 = ((quad + 4) ^ (n16 & 7)) * 8;
  int voff[4];
#pragma unroll
  for (int kc = 0; kc < 4; ++kc)
    voff[kc] = n16 * 64 + (((kc * 2 + (quad >> 1)) ^ (n16 & 7)) * 8) + (quad & 1) * 4;

  const f16* __restrict__ ks = &Ks[kh][0];
  const f16* __restrict__ vs = &Vs[kh][0];

  for (int kt = 0; kt < N_; kt += 128) {
    __syncthreads();
    cp16(&Ks[0][wid * 512], gK0 + (size_t)kt * D_);
    cp16(&Ks[0][2048 + wid * 512], gK1 + (size_t)kt * D_);
    cp16(&Ks[1][wid * 512], gK0 + (size_t)(kt + 64) * D_);
    cp16(&Ks[1][2048 + wid * 512], gK1 + (size_t)(kt + 64) * D_);
    cp16(&Vs[0][wid * 512], gV0 + kt);
    cp16(&Vs[0][2048 + wid * 512], gV1 + kt);
    cp16(&Vs[1][wid * 512], gV0 + kt + 64);
    cp16(&Vs[1][2048 + wid * 512], gV1 + kt + 64);
    __syncthreads();

    // S^T = K @ Q^T for both q-chunks (K-frags read once)
    f32x4 s[2][4];
#pragma unroll
    for (int kc = 0; kc < 4; ++kc) {
      const f16x8 kf0 = *(const f16x8*)(&ks[(kc * 16 + n16) * 64 + fs0]);
      const f16x8 kf1 = *(const f16x8*)(&ks[(kc * 16 + n16) * 64 + fs1]);
#pragma unroll
      for (int qc = 0; qc < 2; ++qc) {
        f32x4 sv = (f32x4){0.f, 0.f, 0.f, 0.f};
        sv = MFMA16(kf0, qf[qc][0], sv);
        sv = MFMA16(kf1, qf[qc][1], sv);
        s[qc][kc] = sv;
      }
    }

    // p = 2^s, in-register cvt to PV A-frags
    f16x4 pa[2][4];
#pragma unroll
    for (int qc = 0; qc < 2; ++qc)
#pragma unroll
      for (int kc = 0; kc < 4; ++kc)
#pragma unroll
        for (int r = 0; r < 4; ++r) {
          float p = __builtin_amdgcn_exp2f(s[qc][kc][r]);
          lsum[qc] += p;
          pa[qc][kc][r] = (f16)p;
        }

    // O += P @ V (V-frags read once, used by both q-chunks)
#pragma unroll
    for (int kc = 0; kc < 4; ++kc)
#pragma unroll
      for (int dt = 0; dt < 4; ++dt) {
        const f16x4 vb = *(const f16x4*)(&vs[dt * 1024 + voff[kc]]);
        o[0][dt] = MFMA16K(pa[0][kc], vb, o[0][dt]);
        o[1][dt] = MFMA16K(pa[1][kc], vb, o[1][dt]);
      }
  }

  // combine key-half partials: kh=1 waves dump to LDS, kh=0 waves add
  __syncthreads();
  float* red = (float*)&Ks[0][0];  // 2 waves x 64 lanes x 36 f32 = 18.4 KB < 32 KB
  if (kh == 1) {
    float* p = red + ((size_t)qh * 64 + lane) * 36;
#pragma unroll
    for (int qc = 0; qc < 2; ++qc)
#pragma unroll
      for (int dt = 0; dt < 4; ++dt)
        *(f32x4*)(p + (qc * 4 + dt) * 4) = o[qc][dt];
    p[32] = lsum[0];
    p[33] = lsum[1];
  }
  __syncthreads();
  if (kh == 0) {
    const float* p = red + ((size_t)qh * 64 + lane) * 36;
#pragma unroll
    for (int qc = 0; qc < 2; ++qc)
#pragma unroll
      for (int dt = 0; dt < 4; ++dt) {
        f32x4 v = *(const f32x4*)(p + (qc * 4 + dt) * 4);
#pragma unroll
        for (int r = 0; r < 4; ++r) o[qc][dt][r] += v[r];
      }
    lsum[0] += p[32];
    lsum[1] += p[33];

#pragma unroll
    for (int qc = 0; qc < 2; ++qc) {
      lsum[qc] += __shfl_xor(lsum[qc], 16);
      lsum[qc] += __shfl_xor(lsum[qc], 32);
    }

#pragma unroll
    for (int qc = 0; qc < 2; ++qc)
#pragma unroll
      for (int r = 0; r < 4; ++r) {
        float inv = 1.0f / __shfl(lsum[qc], quad * 4 + r);
        int nrow = qb + qh * 32 + qc * 16 + quad * 4 + r;
        f16* aop = AO + ((size_t)(b * N_ + nrow)) * H_ + h * 64;
#pragma unroll
        for (int dt = 0; dt < 4; ++dt)
          aop[dt * 16 + n16] = (f16)(o[qc][dt][r] * inv);
      }
  }
}

// ---------------------------------------------------------------------------
// Output GEMM, m97-style: out[4096,1024] = AO_f16 @ WoutT^T + bout (f32 out)
// ---------------------------------------------------------------------------
__global__ __launch_bounds__(256) void out_mfma(
    const f16* __restrict__ A, const f16* __restrict__ Wt,
    const float* __restrict__ bias, float* __restrict__ out) {
  const int bid = blockIdx.x;
  const int rb = (bid & 31) * 128;
  const int cb = (bid >> 5) * 128;
  const int t = threadIdx.x;
  const int lane = t & 63, wid = t >> 6;
  const int quad = lane >> 4, n16 = lane & 15;
  const int wm = wid >> 1, wn = wid & 1;

  __shared__ f16 As[128 * 32];
  __shared__ f16 Bs[128 * 32];

  f32x4 acc[4][4];
#pragma unroll
  for (int i = 0; i < 4; ++i)
#pragma unroll
    for (int j = 0; j < 4; ++j) acc[i][j] = (f32x4){0.f, 0.f, 0.f, 0.f};

  int srow0 = wid * 16 + (lane >> 2);
  int srow1 = 64 + srow0;
  int gl0 = ((lane & 3) ^ ((srow0 >> 1) & 3)) * 8;
  int gl1 = ((lane & 3) ^ ((srow1 >> 1) & 3)) * 8;
  const f16* gA0 = A + (size_t)(rb + srow0) * H_ + gl0;
  const f16* gA1 = A + (size_t)(rb + srow1) * H_ + gl1;
  const f16* gB0 = Wt + (size_t)(cb + srow0) * H_ + gl0;
  const f16* gB1 = Wt + (size_t)(cb + srow1) * H_ + gl1;
  f16* lA0 = &As[wid * 512];
  f16* lA1 = &As[2048 + wid * 512];
  f16* lB0 = &Bs[wid * 512];
  f16* lB1 = &Bs[2048 + wid * 512];

  const int fsw = (quad ^ ((n16 >> 1) & 3)) * 8;
  int aoff[4], boff[4];
#pragma unroll
  for (int i = 0; i < 4; ++i) {
    aoff[i] = (wm * 64 + i * 16 + n16) * 32 + fsw;
    boff[i] = (wn * 64 + i * 16 + n16) * 32 + fsw;
  }

  for (int kt = 0; kt < H_; kt += 32) {
    __syncthreads();
    cp16(lA0, gA0); cp16(lA1, gA1);
    cp16(lB0, gB0); cp16(lB1, gB1);
    gA0 += 32; gA1 += 32; gB0 += 32; gB1 += 32;
    __syncthreads();

    f16x8 af[4], bf[4];
#pragma unroll
    for (int mt = 0; mt < 4; ++mt) af[mt] = *(const f16x8*)(&As[aoff[mt]]);
#pragma unroll
    for (int nt = 0; nt < 4; ++nt) bf[nt] = *(const f16x8*)(&Bs[boff[nt]]);
#pragma unroll
    for (int mt = 0; mt < 4; ++mt)
#pragma unroll
      for (int nt = 0; nt < 4; ++nt)
        acc[mt][nt] = MFMA16(af[mt], bf[nt], acc[mt][nt]);
  }

#pragma unroll
  for (int nt = 0; nt < 4; ++nt) {
    int gcol = cb + wn * 64 + nt * 16 + n16;
    float bv = bias[gcol];
#pragma unroll
    for (int mt = 0; mt < 4; ++mt)
#pragma unroll
      for (int r = 0; r < 4; ++r) {
        int grow = rb + wm * 64 + mt * 16 + quad * 4 + r;
        out[(size_t)grow * H_ + gcol] = acc[mt][nt][r] + bv;
      }
  }
}

extern "C" void kernel_launch(void* const* d_in, const int* in_sizes, int n_in,
                              void* d_out, int out_size, void* d_ws, size_t ws_size,
                              hipStream_t stream) {
  const float* x    = (const float*)d_in[0];
  const float* x2   = (const float*)d_in[1];
  const float* Wqkv = (const float*)d_in[2];
  const float* Wout = (const float*)d_in[3];
  const float* bout = (const float*)d_in[4];
  float* out = (float*)d_out;

  const size_t per = (size_t)B_ * NH_ * N_ * D_;   // 4M f16 elements
  f16* Xc    = (f16*)d_ws;
  f16* X2c   = Xc + per;
  f16* Qw    = X2c + per;
  f16* Kw    = Qw + per;
  f16* Vw    = Kw + per;
  f16* Vtw   = Vw + per;
  f16* AO    = Vtw + per;
  f16* WqkvT = AO + per;                      // [3072][1024]
  f16* WoutT = WqkvT + (size_t)3072 * 1024;   // [1024][1024]

  convf16<<<dim3(2048, 2), 256, 0, stream>>>(x, x2, Xc, X2c);
  transw<<<dim3(48, 16), 256, 0, stream>>>(Wqkv, WqkvT, H_, 3 * H_);
  transw<<<dim3(16, 16), 256, 0, stream>>>(Wout, WoutT, H_, H_);
  qkv_mfma<<<dim3(768), 256, 0, stream>>>(Xc, X2c, WqkvT, Qw, Kw, Vw);
  transv<<<dim3(32, 32), 256, 0, stream>>>(Vw, Vtw);
  attn4<<<dim3(32, 32), 256, 0, stream>>>(Qw, Kw, Vtw, AO);
  out_mfma<<<dim3(256), 256, 0, stream>>>(AO, WoutT, bout, out);
}

// Round 8
// 214.279 us; speedup vs baseline: 1.0169x; 1.0169x over previous
//
#include <hip/hip_runtime.h>

#define B_ 2
#define N_ 2048
#define H_ 1024
#define NH_ 16
#define D_ 64

typedef _Float16 f16;
typedef _Float16 f16x2 __attribute__((ext_vector_type(2)));
typedef _Float16 f16x4 __attribute__((ext_vector_type(4)));
typedef _Float16 f16x8 __attribute__((ext_vector_type(8)));
typedef float f32x4 __attribute__((ext_vector_type(4)));

#define MFMA16(a, b, c) __builtin_amdgcn_mfma_f32_16x16x32_f16((a), (b), (c), 0, 0, 0)
#define MFMA16K(a, b, c) __builtin_amdgcn_mfma_f32_16x16x16f16((a), (b), (c), 0, 0, 0)

// async global->LDS, 16B per lane; lds dest = base + lane*16 (wave-uniform base)
__device__ __forceinline__ void cp16(void* lds, const void* g) {
  __builtin_amdgcn_global_load_lds(
      (const __attribute__((address_space(1))) void*)g,
      (__attribute__((address_space(3))) void*)lds, 16, 0, 0);
}

__device__ __forceinline__ f16x4 pk4(float a, float b, float c, float d) {
  auto lo = __builtin_amdgcn_cvt_pkrtz(a, b);   // __fp16 ext_vector(2)
  auto hi = __builtin_amdgcn_cvt_pkrtz(c, d);
  f16x4 r;
  r[0] = (f16)lo[0]; r[1] = (f16)lo[1]; r[2] = (f16)hi[0]; r[3] = (f16)hi[1];
  return r;
}

// ---------------------------------------------------------------------------
// prep: fused (a) x,x2 f32->f16 convert  (b) Wqkv transpose+cvt  (c) Wout
// transpose+cvt.  One launch instead of three (launch overhead ~10us each).
//   bid <  4096          : convert (2048 blocks per tensor)
//   4096 <= bid < 4864   : Wqkv^T [3072][1024]
//   4864 <= bid < 5120   : Wout^T [1024][1024]
// ---------------------------------------------------------------------------
__global__ __launch_bounds__(256) void prep(
    const float* __restrict__ x, const float* __restrict__ x2,
    f16* __restrict__ xo, f16* __restrict__ x2o,
    const float* __restrict__ Wqkv, f16* __restrict__ WqkvT,
    const float* __restrict__ Wout, f16* __restrict__ WoutT) {
  const int bid = blockIdx.x;
  const int t = threadIdx.x;

  if (bid < 4096) {
    const float* __restrict__ src = (bid < 2048) ? x : x2;
    f16* __restrict__ dst = (bid < 2048) ? xo : x2o;
    const size_t i = ((size_t)(bid & 2047) * 256 + t) * 8;
    float4 v0 = ((const float4*)(src + i))[0];
    float4 v1 = ((const float4*)(src + i))[1];
    f16x8 o;
    o[0] = (f16)v0.x; o[1] = (f16)v0.y; o[2] = (f16)v0.z; o[3] = (f16)v0.w;
    o[4] = (f16)v1.x; o[5] = (f16)v1.y; o[6] = (f16)v1.z; o[7] = (f16)v1.w;
    *(f16x8*)(dst + i) = o;
    return;
  }

  // transpose segment
  const float* __restrict__ W;
  f16* __restrict__ Wt;
  int cb, kb, rows, ncols;
  if (bid < 4864) {
    int j = bid - 4096;               // 768 blocks: 48 x 16
    W = Wqkv; Wt = WqkvT; rows = H_; ncols = 3 * H_;
    cb = (j % 48) * 64; kb = (j / 48) * 64;
  } else {
    int j = bid - 4864;               // 256 blocks: 16 x 16
    W = Wout; Wt = WoutT; rows = H_; ncols = H_;
    cb = (j & 15) * 64; kb = (j >> 4) * 64;
  }

  __shared__ f16 T[64][72];
  {
    const int k = t >> 2, c0 = (t & 3) * 16;
    const float* wp = W + (size_t)(kb + k) * ncols + cb + c0;
    float4 w0 = ((const float4*)wp)[0];
    float4 w1 = ((const float4*)wp)[1];
    float4 w2 = ((const float4*)wp)[2];
    float4 w3 = ((const float4*)wp)[3];
    T[c0 + 0][k] = (f16)w0.x;  T[c0 + 1][k] = (f16)w0.y;
    T[c0 + 2][k] = (f16)w0.z;  T[c0 + 3][k] = (f16)w0.w;
    T[c0 + 4][k] = (f16)w1.x;  T[c0 + 5][k] = (f16)w1.y;
    T[c0 + 6][k] = (f16)w1.z;  T[c0 + 7][k] = (f16)w1.w;
    T[c0 + 8][k] = (f16)w2.x;  T[c0 + 9][k] = (f16)w2.y;
    T[c0 + 10][k] = (f16)w2.z; T[c0 + 11][k] = (f16)w2.w;
    T[c0 + 12][k] = (f16)w3.x; T[c0 + 13][k] = (f16)w3.y;
    T[c0 + 14][k] = (f16)w3.z; T[c0 + 15][k] = (f16)w3.w;
  }
  __syncthreads();
  {
    const int c = t >> 2, k0 = (t & 3) * 16;
    f16* op = Wt + (size_t)(cb + c) * rows + kb + k0;
    *(f16x8*)(op + 0) = *(const f16x8*)(&T[c][k0]);
    *(f16x8*)(op + 8) = *(const f16x8*)(&T[c][k0 + 8]);
  }
}

// ---------------------------------------------------------------------------
// QKV GEMM, m97-style. Q,K segments: normal orientation, write [B,NH,N,D].
// V segment: MFMA operands SWAPPED (computes C^T in-register) so the epilogue
// writes V^T [bh][d][n] directly with identical coalescing — transv kernel
// eliminated for free. Q scaled by 0.125*log2(e) (exp2 softmax downstream).
// ---------------------------------------------------------------------------
__global__ __launch_bounds__(256) void qkv_mfma(
    const f16* __restrict__ Xc, const f16* __restrict__ X2c,
    const f16* __restrict__ Wt, f16* __restrict__ Qo,
    f16* __restrict__ Ko, f16* __restrict__ Vto) {
  const int bid = blockIdx.x;
  const int rb = (bid & 31) * 128;
  const int cb = (bid >> 5) * 128;
  const int t = threadIdx.x;
  const int lane = t & 63, wid = t >> 6;
  const int quad = lane >> 4, n16 = lane & 15;
  const int wm = wid >> 1, wn = wid & 1;

  const f16* __restrict__ A = (cb < H_) ? Xc : X2c;
  const int seg = cb >> 10;
  const float qscale = (seg == 0) ? 0.125f * 1.44269504f : 1.0f;

  __shared__ f16 As[128 * 32];
  __shared__ f16 Bs[128 * 32];

  f32x4 acc[4][4];
#pragma unroll
  for (int i = 0; i < 4; ++i)
#pragma unroll
    for (int j = 0; j < 4; ++j) acc[i][j] = (f32x4){0.f, 0.f, 0.f, 0.f};

  int srow0 = wid * 16 + (lane >> 2);
  int srow1 = 64 + srow0;
  int gl0 = ((lane & 3) ^ ((srow0 >> 1) & 3)) * 8;
  int gl1 = ((lane & 3) ^ ((srow1 >> 1) & 3)) * 8;
  const f16* gA0 = A + (size_t)(rb + srow0) * H_ + gl0;
  const f16* gA1 = A + (size_t)(rb + srow1) * H_ + gl1;
  const f16* gB0 = Wt + (size_t)(cb + srow0) * H_ + gl0;
  const f16* gB1 = Wt + (size_t)(cb + srow1) * H_ + gl1;
  f16* lA0 = &As[wid * 512];
  f16* lA1 = &As[2048 + wid * 512];
  f16* lB0 = &Bs[wid * 512];
  f16* lB1 = &Bs[2048 + wid * 512];

  const int fsw = (quad ^ ((n16 >> 1) & 3)) * 8;
  int aoff[4], boff[4];
#pragma unroll
  for (int i = 0; i < 4; ++i) {
    aoff[i] = (wm * 64 + i * 16 + n16) * 32 + fsw;
    boff[i] = (wn * 64 + i * 16 + n16) * 32 + fsw;
  }

  const bool vseg = (seg == 2);
  for (int kt = 0; kt < H_; kt += 32) {
    __syncthreads();
    cp16(lA0, gA0); cp16(lA1, gA1);
    cp16(lB0, gB0); cp16(lB1, gB1);
    gA0 += 32; gA1 += 32; gB0 += 32; gB1 += 32;
    __syncthreads();

    f16x8 af[4], bf[4];
#pragma unroll
    for (int mt = 0; mt < 4; ++mt) af[mt] = *(const f16x8*)(&As[aoff[mt]]);
#pragma unroll
    for (int nt = 0; nt < 4; ++nt) bf[nt] = *(const f16x8*)(&Bs[boff[nt]]);
    if (!vseg) {
#pragma unroll
      for (int mt = 0; mt < 4; ++mt)
#pragma unroll
        for (int nt = 0; nt < 4; ++nt)
          acc[mt][nt] = MFMA16(af[mt], bf[nt], acc[mt][nt]);
    } else {
      // swapped: acc holds C^T tile (lane: row-dim = n16, col-dim = quad*4+r)
#pragma unroll
      for (int mt = 0; mt < 4; ++mt)
#pragma unroll
        for (int nt = 0; nt < 4; ++nt)
          acc[mt][nt] = MFMA16(bf[nt], af[mt], acc[mt][nt]);
    }
  }

  if (!vseg) {
    f16* __restrict__ outp = (seg == 0) ? Qo : Ko;
#pragma unroll
    for (int mt = 0; mt < 4; ++mt)
#pragma unroll
      for (int nt = 0; nt < 4; ++nt)
#pragma unroll
        for (int r = 0; r < 4; ++r) {
          int grow = rb + wm * 64 + mt * 16 + quad * 4 + r;
          int gcol = cb + wn * 64 + nt * 16 + n16;
          int bb = grow >> 11, nn = grow & 2047;
          int hh = (gcol >> 6) & 15, dd = gcol & 63;
          outp[(((size_t)(bb * NH_ + hh)) * N_ + nn) * D_ + dd] =
              (f16)(acc[mt][nt][r] * qscale);
        }
  } else {
    // V^T write: [bh][d][n]; lanes n16 -> consecutive n (32B segments)
#pragma unroll
    for (int mt = 0; mt < 4; ++mt)
#pragma unroll
      for (int nt = 0; nt < 4; ++nt)
#pragma unroll
        for (int r = 0; r < 4; ++r) {
          int gcol = cb + wn * 64 + nt * 16 + quad * 4 + r;   // col = head*64+d
          int grow = rb + wm * 64 + mt * 16 + n16;            // row = b*2048+n
          int bb = grow >> 11, nn = grow & 2047;
          int hh = (gcol >> 6) & 15, dd = gcol & 63;
          Vto[(((size_t)(bb * NH_ + hh)) * D_ + dd) * N_ + nn] =
              (f16)acc[mt][nt][r];
        }
  }
}

// ---------------------------------------------------------------------------
// Flash attention v5: key-split waves (R6) + VALU-lean softmax.
// Block: 64 queries x 128-key tiles, wave = (qh, kh) covers 32 q x 64 keys.
// lsum computed by an extra ones-vector MFMA per kc: result lands in the SAME
// register layout as O (row=query=quad*4+r), so normalization needs no shfl
// and no per-element adds. P cvt via packed cvt_pkrtz. P stays in registers.
// ---------------------------------------------------------------------------
__global__ __launch_bounds__(256) void attn5(
    const f16* __restrict__ Q, const f16* __restrict__ K,
    const f16* __restrict__ Vt, f16* __restrict__ AO) {
  const int bh = blockIdx.y;
  const int b = bh >> 4, h = bh & 15;
  const int qb = blockIdx.x * 64;
  const int t = threadIdx.x;
  const int lane = t & 63, wid = t >> 6;
  const int quad = lane >> 4, n16 = lane & 15;
  const int qh = wid & 1;   // query half
  const int kh = wid >> 1;  // key half

  const f16* __restrict__ Qp = Q + (size_t)bh * N_ * D_;
  const f16* __restrict__ Kp = K + (size_t)bh * N_ * D_;
  const f16* __restrict__ Vp = Vt + (size_t)bh * D_ * N_;  // [d][n]

  __shared__ f16 Ks[2][64 * 64];  // [kh][key][d], XOR-8 granule swizzle
  __shared__ f16 Vs[2][64 * 64];  // [kh][d][key], XOR-8 granule swizzle

  f16x8 qf[2][2];
#pragma unroll
  for (int qc = 0; qc < 2; ++qc) {
    const f16* qp = Qp + (size_t)(qb + qh * 32 + qc * 16 + n16) * D_ + quad * 8;
    qf[qc][0] = *(const f16x8*)(qp);
    qf[qc][1] = *(const f16x8*)(qp + 32);
  }

  f32x4 o[2][4];
#pragma unroll
  for (int i = 0; i < 2; ++i)
#pragma unroll
    for (int j = 0; j < 4; ++j) o[i][j] = (f32x4){0.f, 0.f, 0.f, 0.f};
  f32x4 lacc[2];
  lacc[0] = (f32x4){0.f, 0.f, 0.f, 0.f};
  lacc[1] = (f32x4){0.f, 0.f, 0.f, 0.f};
  const f16x4 onesb = (f16x4){(f16)1.f, (f16)1.f, (f16)1.f, (f16)1.f};

  const int srow0 = wid * 8 + (lane >> 3);
  const int srow1 = 32 + srow0;
  const int gl0 = ((lane & 7) ^ (srow0 & 7)) * 8;
  const int gl1 = ((lane & 7) ^ (srow1 & 7)) * 8;
  const f16* gK0 = Kp + (size_t)srow0 * D_ + gl0;
  const f16* gK1 = Kp + (size_t)srow1 * D_ + gl1;
  const f16* gV0 = Vp + (size_t)srow0 * N_ + gl0;
  const f16* gV1 = Vp + (size_t)srow1 * N_ + gl1;

  const int fs0 = (quad ^ (n16 & 7)) * 8;
  const int fs1 = ((quad + 4) ^ (n16 & 7)) * 8;
  int voff[4];
#pragma unroll
  for (int kc = 0; kc < 4; ++kc)
    voff[kc] = n16 * 64 + (((kc * 2 + (quad >> 1)) ^ (n16 & 7)) * 8) + (quad & 1) * 4;

  const f16* __restrict__ ks = &Ks[kh][0];
  const f16* __restrict__ vs = &Vs[kh][0];

  for (int kt = 0; kt < N_; kt += 128) {
    __syncthreads();
    cp16(&Ks[0][wid * 512], gK0 + (size_t)kt * D_);
    cp16(&Ks[0][2048 + wid * 512], gK1 + (size_t)kt * D_);
    cp16(&Ks[1][wid * 512], gK0 + (size_t)(kt + 64) * D_);
    cp16(&Ks[1][2048 + wid * 512], gK1 + (size_t)(kt + 64) * D_);
    cp16(&Vs[0][wid * 512], gV0 + kt);
    cp16(&Vs[0][2048 + wid * 512], gV1 + kt);
    cp16(&Vs[1][wid * 512], gV0 + kt + 64);
    cp16(&Vs[1][2048 + wid * 512], gV1 + kt + 64);
    __syncthreads();

    // S^T = K @ Q^T for both q-chunks (K-frags read once)
    f32x4 s[2][4];
#pragma unroll
    for (int kc = 0; kc < 4; ++kc) {
      const f16x8 kf0 = *(const f16x8*)(&ks[(kc * 16 + n16) * 64 + fs0]);
      const f16x8 kf1 = *(const f16x8*)(&ks[(kc * 16 + n16) * 64 + fs1]);
#pragma unroll
      for (int qc = 0; qc < 2; ++qc) {
        f32x4 sv = (f32x4){0.f, 0.f, 0.f, 0.f};
        sv = MFMA16(kf0, qf[qc][0], sv);
        sv = MFMA16(kf1, qf[qc][1], sv);
        s[qc][kc] = sv;
      }
    }

    // p = 2^s (log2e folded into Q); packed cvt; lsum via ones-MFMA
    f16x4 pa[2][4];
#pragma unroll
    for (int qc = 0; qc < 2; ++qc)
#pragma unroll
      for (int kc = 0; kc < 4; ++kc) {
        float p0 = __builtin_amdgcn_exp2f(s[qc][kc][0]);
        float p1 = __builtin_amdgcn_exp2f(s[qc][kc][1]);
        float p2 = __builtin_amdgcn_exp2f(s[qc][kc][2]);
        float p3 = __builtin_amdgcn_exp2f(s[qc][kc][3]);
        pa[qc][kc] = pk4(p0, p1, p2, p3);
      }
#pragma unroll
    for (int kc = 0; kc < 4; ++kc) {
      lacc[0] = MFMA16K(pa[0][kc], onesb, lacc[0]);
      lacc[1] = MFMA16K(pa[1][kc], onesb, lacc[1]);
    }

    // O += P @ V (V-frags read once, used by both q-chunks)
#pragma unroll
    for (int kc = 0; kc < 4; ++kc)
#pragma unroll
      for (int dt = 0; dt < 4; ++dt) {
        const f16x4 vb = *(const f16x4*)(&vs[dt * 1024 + voff[kc]]);
        o[0][dt] = MFMA16K(pa[0][kc], vb, o[0][dt]);
        o[1][dt] = MFMA16K(pa[1][kc], vb, o[1][dt]);
      }
  }

  // combine key-half partials (O + lacc), then normalize (no shfl needed:
  // lacc reg r corresponds to query quad*4+r, same as o reg r)
  __syncthreads();
  float* red = (float*)&Ks[0][0];  // 2 waves x 64 lanes x 40 f32 = 20 KB
  if (kh == 1) {
    float* p = red + ((size_t)(qh * 64 + lane)) * 40;
#pragma unroll
    for (int qc = 0; qc < 2; ++qc) {
#pragma unroll
      for (int dt = 0; dt < 4; ++dt)
        *(f32x4*)(p + (qc * 4 + dt) * 4) = o[qc][dt];
      *(f32x4*)(p + 32 + qc * 4) = lacc[qc];
    }
  }
  __syncthreads();
  if (kh == 0) {
    const float* p = red + ((size_t)(qh * 64 + lane)) * 40;
#pragma unroll
    for (int qc = 0; qc < 2; ++qc) {
#pragma unroll
      for (int dt = 0; dt < 4; ++dt) {
        f32x4 v = *(const f32x4*)(p + (qc * 4 + dt) * 4);
#pragma unroll
        for (int r = 0; r < 4; ++r) o[qc][dt][r] += v[r];
      }
      f32x4 lv = *(const f32x4*)(p + 32 + qc * 4);
#pragma unroll
      for (int r = 0; r < 4; ++r) lacc[qc][r] += lv[r];
    }

#pragma unroll
    for (int qc = 0; qc < 2; ++qc)
#pragma unroll
      for (int r = 0; r < 4; ++r) {
        float inv = 1.0f / lacc[qc][r];
        int nrow = qb + qh * 32 + qc * 16 + quad * 4 + r;
        f16* aop = AO + ((size_t)(b * N_ + nrow)) * H_ + h * 64;
#pragma unroll
        for (int dt = 0; dt < 4; ++dt)
          aop[dt * 16 + n16] = (f16)(o[qc][dt][r] * inv);
      }
  }
}

// ---------------------------------------------------------------------------
// Output GEMM, m97-style: out[4096,1024] = AO_f16 @ WoutT^T + bout (f32 out)
// ---------------------------------------------------------------------------
__global__ __launch_bounds__(256) void out_mfma(
    const f16* __restrict__ A, const f16* __restrict__ Wt,
    const float* __restrict__ bias, float* __restrict__ out) {
  const int bid = blockIdx.x;
  const int rb = (bid & 31) * 128;
  const int cb = (bid >> 5) * 128;
  const int t = threadIdx.x;
  const int lane = t & 63, wid = t >> 6;
  const int quad = lane >> 4, n16 = lane & 15;
  const int wm = wid >> 1, wn = wid & 1;

  __shared__ f16 As[128 * 32];
  __shared__ f16 Bs[128 * 32];

  f32x4 acc[4][4];
#pragma unroll
  for (int i = 0; i < 4; ++i)
#pragma unroll
    for (int j = 0; j < 4; ++j) acc[i][j] = (f32x4){0.f, 0.f, 0.f, 0.f};

  int srow0 = wid * 16 + (lane >> 2);
  int srow1 = 64 + srow0;
  int gl0 = ((lane & 3) ^ ((srow0 >> 1) & 3)) * 8;
  int gl1 = ((lane & 3) ^ ((srow1 >> 1) & 3)) * 8;
  const f16* gA0 = A + (size_t)(rb + srow0) * H_ + gl0;
  const f16* gA1 = A + (size_t)(rb + srow1) * H_ + gl1;
  const f16* gB0 = Wt + (size_t)(cb + srow0) * H_ + gl0;
  const f16* gB1 = Wt + (size_t)(cb + srow1) * H_ + gl1;
  f16* lA0 = &As[wid * 512];
  f16* lA1 = &As[2048 + wid * 512];
  f16* lB0 = &Bs[wid * 512];
  f16* lB1 = &Bs[2048 + wid * 512];

  const int fsw = (quad ^ ((n16 >> 1) & 3)) * 8;
  int aoff[4], boff[4];
#pragma unroll
  for (int i = 0; i < 4; ++i) {
    aoff[i] = (wm * 64 + i * 16 + n16) * 32 + fsw;
    boff[i] = (wn * 64 + i * 16 + n16) * 32 + fsw;
  }

  for (int kt = 0; kt < H_; kt += 32) {
    __syncthreads();
    cp16(lA0, gA0); cp16(lA1, gA1);
    cp16(lB0, gB0); cp16(lB1, gB1);
    gA0 += 32; gA1 += 32; gB0 += 32; gB1 += 32;
    __syncthreads();

    f16x8 af[4], bf[4];
#pragma unroll
    for (int mt = 0; mt < 4; ++mt) af[mt] = *(const f16x8*)(&As[aoff[mt]]);
#pragma unroll
    for (int nt = 0; nt < 4; ++nt) bf[nt] = *(const f16x8*)(&Bs[boff[nt]]);
#pragma unroll
    for (int mt = 0; mt < 4; ++mt)
#pragma unroll
      for (int nt = 0; nt < 4; ++nt)
        acc[mt][nt] = MFMA16(af[mt], bf[nt], acc[mt][nt]);
  }

#pragma unroll
  for (int nt = 0; nt < 4; ++nt) {
    int gcol = cb + wn * 64 + nt * 16 + n16;
    float bv = bias[gcol];
#pragma unroll
    for (int mt = 0; mt < 4; ++mt)
#pragma unroll
      for (int r = 0; r < 4; ++r) {
        int grow = rb + wm * 64 + mt * 16 + quad * 4 + r;
        out[(size_t)grow * H_ + gcol] = acc[mt][nt][r] + bv;
      }
  }
}

extern "C" void kernel_launch(void* const* d_in, const int* in_sizes, int n_in,
                              void* d_out, int out_size, void* d_ws, size_t ws_size,
                              hipStream_t stream) {
  const float* x    = (const float*)d_in[0];
  const float* x2   = (const float*)d_in[1];
  const float* Wqkv = (const float*)d_in[2];
  const float* Wout = (const float*)d_in[3];
  const float* bout = (const float*)d_in[4];
  float* out = (float*)d_out;

  const size_t per = (size_t)B_ * NH_ * N_ * D_;   // 4M f16 elements
  f16* Xc    = (f16*)d_ws;
  f16* X2c   = Xc + per;
  f16* Qw    = X2c + per;
  f16* Kw    = Qw + per;
  f16* Vtw   = Kw + per;
  f16* AO    = Vtw + per;
  f16* WqkvT = AO + per;                      // [3072][1024]
  f16* WoutT = WqkvT + (size_t)3072 * 1024;   // [1024][1024]

  prep<<<dim3(5120), 256, 0, stream>>>(x, x2, Xc, X2c, Wqkv, WqkvT, Wout, WoutT);
  qkv_mfma<<<dim3(768), 256, 0, stream>>>(Xc, X2c, WqkvT, Qw, Kw, Vtw);
  attn5<<<dim3(32, 32), 256, 0, stream>>>(Qw, Kw, Vtw, AO);
  out_mfma<<<dim3(256), 256, 0, stream>>>(AO, WoutT, bout, out);
}

// Round 9
// 203.646 us; speedup vs baseline: 1.0699x; 1.0522x over previous
//
#include <hip/hip_runtime.h>

#define B_ 2
#define N_ 2048
#define H_ 1024
#define NH_ 16
#define D_ 64

typedef _Float16 f16;
typedef _Float16 f16x2 __attribute__((ext_vector_type(2)));
typedef _Float16 f16x4 __attribute__((ext_vector_type(4)));
typedef _Float16 f16x8 __attribute__((ext_vector_type(8)));
typedef float f32x4 __attribute__((ext_vector_type(4)));

#define MFMA16(a, b, c) __builtin_amdgcn_mfma_f32_16x16x32_f16((a), (b), (c), 0, 0, 0)
#define MFMA16K(a, b, c) __builtin_amdgcn_mfma_f32_16x16x16f16((a), (b), (c), 0, 0, 0)

// async global->LDS, 16B per lane; lds dest = base + lane*16 (wave-uniform base)
__device__ __forceinline__ void cp16(void* lds, const void* g) {
  __builtin_amdgcn_global_load_lds(
      (const __attribute__((address_space(1))) void*)g,
      (__attribute__((address_space(3))) void*)lds, 16, 0, 0);
}

__device__ __forceinline__ f16x4 pk4(float a, float b, float c, float d) {
  auto lo = __builtin_amdgcn_cvt_pkrtz(a, b);   // __fp16 ext_vector(2)
  auto hi = __builtin_amdgcn_cvt_pkrtz(c, d);
  f16x4 r;
  r[0] = (f16)lo[0]; r[1] = (f16)lo[1]; r[2] = (f16)hi[0]; r[3] = (f16)hi[1];
  return r;
}

// ---------------------------------------------------------------------------
// prep: fused (a) x,x2 f32->f16 convert  (b) Wqkv transpose+cvt  (c) Wout
// transpose+cvt.
// ---------------------------------------------------------------------------
__global__ __launch_bounds__(256) void prep(
    const float* __restrict__ x, const float* __restrict__ x2,
    f16* __restrict__ xo, f16* __restrict__ x2o,
    const float* __restrict__ Wqkv, f16* __restrict__ WqkvT,
    const float* __restrict__ Wout, f16* __restrict__ WoutT) {
  const int bid = blockIdx.x;
  const int t = threadIdx.x;

  if (bid < 4096) {
    const float* __restrict__ src = (bid < 2048) ? x : x2;
    f16* __restrict__ dst = (bid < 2048) ? xo : x2o;
    const size_t i = ((size_t)(bid & 2047) * 256 + t) * 8;
    float4 v0 = ((const float4*)(src + i))[0];
    float4 v1 = ((const float4*)(src + i))[1];
    f16x8 o;
    o[0] = (f16)v0.x; o[1] = (f16)v0.y; o[2] = (f16)v0.z; o[3] = (f16)v0.w;
    o[4] = (f16)v1.x; o[5] = (f16)v1.y; o[6] = (f16)v1.z; o[7] = (f16)v1.w;
    *(f16x8*)(dst + i) = o;
    return;
  }

  const float* __restrict__ W;
  f16* __restrict__ Wt;
  int cb, kb, rows, ncols;
  if (bid < 4864) {
    int j = bid - 4096;               // 768 blocks: 48 x 16
    W = Wqkv; Wt = WqkvT; rows = H_; ncols = 3 * H_;
    cb = (j % 48) * 64; kb = (j / 48) * 64;
  } else {
    int j = bid - 4864;               // 256 blocks: 16 x 16
    W = Wout; Wt = WoutT; rows = H_; ncols = H_;
    cb = (j & 15) * 64; kb = (j >> 4) * 64;
  }

  __shared__ f16 T[64][72];
  {
    const int k = t >> 2, c0 = (t & 3) * 16;
    const float* wp = W + (size_t)(kb + k) * ncols + cb + c0;
    float4 w0 = ((const float4*)wp)[0];
    float4 w1 = ((const float4*)wp)[1];
    float4 w2 = ((const float4*)wp)[2];
    float4 w3 = ((const float4*)wp)[3];
    T[c0 + 0][k] = (f16)w0.x;  T[c0 + 1][k] = (f16)w0.y;
    T[c0 + 2][k] = (f16)w0.z;  T[c0 + 3][k] = (f16)w0.w;
    T[c0 + 4][k] = (f16)w1.x;  T[c0 + 5][k] = (f16)w1.y;
    T[c0 + 6][k] = (f16)w1.z;  T[c0 + 7][k] = (f16)w1.w;
    T[c0 + 8][k] = (f16)w2.x;  T[c0 + 9][k] = (f16)w2.y;
    T[c0 + 10][k] = (f16)w2.z; T[c0 + 11][k] = (f16)w2.w;
    T[c0 + 12][k] = (f16)w3.x; T[c0 + 13][k] = (f16)w3.y;
    T[c0 + 14][k] = (f16)w3.z; T[c0 + 15][k] = (f16)w3.w;
  }
  __syncthreads();
  {
    const int c = t >> 2, k0 = (t & 3) * 16;
    f16* op = Wt + (size_t)(cb + c) * rows + kb + k0;
    *(f16x8*)(op + 0) = *(const f16x8*)(&T[c][k0]);
    *(f16x8*)(op + 8) = *(const f16x8*)(&T[c][k0 + 8]);
  }
}

// ---------------------------------------------------------------------------
// QKV GEMM, m97-style. Q,K segments write [B,NH,N,D]; V segment computes C^T
// via swapped MFMA operands and writes V^T [bh][d][n] directly.
// ---------------------------------------------------------------------------
__global__ __launch_bounds__(256) void qkv_mfma(
    const f16* __restrict__ Xc, const f16* __restrict__ X2c,
    const f16* __restrict__ Wt, f16* __restrict__ Qo,
    f16* __restrict__ Ko, f16* __restrict__ Vto) {
  const int bid = blockIdx.x;
  const int rb = (bid & 31) * 128;
  const int cb = (bid >> 5) * 128;
  const int t = threadIdx.x;
  const int lane = t & 63, wid = t >> 6;
  const int quad = lane >> 4, n16 = lane & 15;
  const int wm = wid >> 1, wn = wid & 1;

  const f16* __restrict__ A = (cb < H_) ? Xc : X2c;
  const int seg = cb >> 10;
  const float qscale = (seg == 0) ? 0.125f * 1.44269504f : 1.0f;

  __shared__ f16 As[128 * 32];
  __shared__ f16 Bs[128 * 32];

  f32x4 acc[4][4];
#pragma unroll
  for (int i = 0; i < 4; ++i)
#pragma unroll
    for (int j = 0; j < 4; ++j) acc[i][j] = (f32x4){0.f, 0.f, 0.f, 0.f};

  int srow0 = wid * 16 + (lane >> 2);
  int srow1 = 64 + srow0;
  int gl0 = ((lane & 3) ^ ((srow0 >> 1) & 3)) * 8;
  int gl1 = ((lane & 3) ^ ((srow1 >> 1) & 3)) * 8;
  const f16* gA0 = A + (size_t)(rb + srow0) * H_ + gl0;
  const f16* gA1 = A + (size_t)(rb + srow1) * H_ + gl1;
  const f16* gB0 = Wt + (size_t)(cb + srow0) * H_ + gl0;
  const f16* gB1 = Wt + (size_t)(cb + srow1) * H_ + gl1;
  f16* lA0 = &As[wid * 512];
  f16* lA1 = &As[2048 + wid * 512];
  f16* lB0 = &Bs[wid * 512];
  f16* lB1 = &Bs[2048 + wid * 512];

  const int fsw = (quad ^ ((n16 >> 1) & 3)) * 8;
  int aoff[4], boff[4];
#pragma unroll
  for (int i = 0; i < 4; ++i) {
    aoff[i] = (wm * 64 + i * 16 + n16) * 32 + fsw;
    boff[i] = (wn * 64 + i * 16 + n16) * 32 + fsw;
  }

  const bool vseg = (seg == 2);
  for (int kt = 0; kt < H_; kt += 32) {
    __syncthreads();
    cp16(lA0, gA0); cp16(lA1, gA1);
    cp16(lB0, gB0); cp16(lB1, gB1);
    gA0 += 32; gA1 += 32; gB0 += 32; gB1 += 32;
    __syncthreads();

    f16x8 af[4], bf[4];
#pragma unroll
    for (int mt = 0; mt < 4; ++mt) af[mt] = *(const f16x8*)(&As[aoff[mt]]);
#pragma unroll
    for (int nt = 0; nt < 4; ++nt) bf[nt] = *(const f16x8*)(&Bs[boff[nt]]);
    if (!vseg) {
#pragma unroll
      for (int mt = 0; mt < 4; ++mt)
#pragma unroll
        for (int nt = 0; nt < 4; ++nt)
          acc[mt][nt] = MFMA16(af[mt], bf[nt], acc[mt][nt]);
    } else {
#pragma unroll
      for (int mt = 0; mt < 4; ++mt)
#pragma unroll
        for (int nt = 0; nt < 4; ++nt)
          acc[mt][nt] = MFMA16(bf[nt], af[mt], acc[mt][nt]);
    }
  }

  if (!vseg) {
    f16* __restrict__ outp = (seg == 0) ? Qo : Ko;
#pragma unroll
    for (int mt = 0; mt < 4; ++mt)
#pragma unroll
      for (int nt = 0; nt < 4; ++nt)
#pragma unroll
        for (int r = 0; r < 4; ++r) {
          int grow = rb + wm * 64 + mt * 16 + quad * 4 + r;
          int gcol = cb + wn * 64 + nt * 16 + n16;
          int bb = grow >> 11, nn = grow & 2047;
          int hh = (gcol >> 6) & 15, dd = gcol & 63;
          outp[(((size_t)(bb * NH_ + hh)) * N_ + nn) * D_ + dd] =
              (f16)(acc[mt][nt][r] * qscale);
        }
  } else {
#pragma unroll
    for (int mt = 0; mt < 4; ++mt)
#pragma unroll
      for (int nt = 0; nt < 4; ++nt)
#pragma unroll
        for (int r = 0; r < 4; ++r) {
          int gcol = cb + wn * 64 + nt * 16 + quad * 4 + r;   // col = head*64+d
          int grow = rb + wm * 64 + mt * 16 + n16;            // row = b*2048+n
          int bb = grow >> 11, nn = grow & 2047;
          int hh = (gcol >> 6) & 15, dd = gcol & 63;
          Vto[(((size_t)(bb * NH_ + hh)) * D_ + dd) * N_ + nn] =
              (f16)acc[mt][nt][r];
        }
  }
}

// ---------------------------------------------------------------------------
// Flash attention v6: double-buffered K/V DMA + 128 queries/block.
// 512 threads = 8 waves: wave = (qg = wid>>1 in 0..3, kh = wid&1).
// Each wave: 32 queries (2 chunks of 16) x its 64-key half of a 128-key tile.
// K/V staged once per 128 queries (half the DMA of v5); prefetch of tile i+1
// issued right after the barrier, computing tile i meanwhile — hides the
// vmcnt(0) barrier drain that bound v1..v5 at ~64us.
// smem layout (64 KB): Ks(buf,kh)=smem+buf*8192+kh*4096;
//                      Vs(buf,kh)=smem+16384+buf*8192+kh*4096. (f16 elems)
// ---------------------------------------------------------------------------
__global__ __launch_bounds__(512) void attn6(
    const f16* __restrict__ Q, const f16* __restrict__ K,
    const f16* __restrict__ Vt, f16* __restrict__ AO) {
  const int bh = blockIdx.y;
  const int b = bh >> 4, h = bh & 15;
  const int qb = blockIdx.x * 128;
  const int t = threadIdx.x;
  const int lane = t & 63, wid = t >> 6;
  const int quad = lane >> 4, n16 = lane & 15;
  const int qg = wid >> 1;  // query group (0..3)
  const int kh = wid & 1;   // key half

  const f16* __restrict__ Qp = Q + (size_t)bh * N_ * D_;
  const f16* __restrict__ Kp = K + (size_t)bh * N_ * D_;
  const f16* __restrict__ Vp = Vt + (size_t)bh * D_ * N_;  // [d][n]

  __shared__ f16 smem[32768];  // 64 KB: [K dbuf 32KB][V dbuf 32KB]

  // Q B-frags: 2 chunks of 16 queries
  f16x8 qf[2][2];
#pragma unroll
  for (int qc = 0; qc < 2; ++qc) {
    const f16* qp = Qp + (size_t)(qb + qg * 32 + qc * 16 + n16) * D_ + quad * 8;
    qf[qc][0] = *(const f16x8*)(qp);
    qf[qc][1] = *(const f16x8*)(qp + 32);
  }

  f32x4 o[2][4];
#pragma unroll
  for (int i = 0; i < 2; ++i)
#pragma unroll
    for (int j = 0; j < 4; ++j) o[i][j] = (f32x4){0.f, 0.f, 0.f, 0.f};
  f32x4 lacc[2];
  lacc[0] = (f32x4){0.f, 0.f, 0.f, 0.f};
  lacc[1] = (f32x4){0.f, 0.f, 0.f, 0.f};
  const f16x4 onesb = (f16x4){(f16)1.f, (f16)1.f, (f16)1.f, (f16)1.f};

  // staging: 512 threads cover one 8KB region (64 rows x 128B) per cp16;
  // thread t -> row t>>3, swizzled granule (t&7)^(row&7)
  const int srow = t >> 3;
  const int sgl = ((t & 7) ^ (srow & 7)) * 8;
  const f16* gK = Kp + (size_t)srow * D_ + sgl;
  const f16* gV = Vp + (size_t)srow * N_ + sgl;

  // fragment granule offsets (logical ^ row&7 swizzle)
  const int fs0 = (quad ^ (n16 & 7)) * 8;
  const int fs1 = ((quad + 4) ^ (n16 & 7)) * 8;
  int voff[4];
#pragma unroll
  for (int kc = 0; kc < 4; ++kc)
    voff[kc] = n16 * 64 + (((kc * 2 + (quad >> 1)) ^ (n16 & 7)) * 8) + (quad & 1) * 4;

  // preload tile 0 into buf 0
  {
    f16* kb = smem;            // buf 0
    f16* vb = smem + 16384;
    cp16(kb + wid * 512, gK);
    cp16(kb + 4096 + wid * 512, gK + (size_t)64 * D_);
    cp16(vb + wid * 512, gV);
    cp16(vb + 4096 + wid * 512, gV + 64);
  }

  for (int i = 0; i < 16; ++i) {
    __syncthreads();   // drains tile-i DMA; prior compute done before overwrite
    if (i < 15) {
      const int nk = (i + 1) * 128;
      const int nb = (i + 1) & 1;
      f16* kb = smem + nb * 8192;
      f16* vb = smem + 16384 + nb * 8192;
      cp16(kb + wid * 512, gK + (size_t)nk * D_);
      cp16(kb + 4096 + wid * 512, gK + (size_t)(nk + 64) * D_);
      cp16(vb + wid * 512, gV + nk);
      cp16(vb + 4096 + wid * 512, gV + nk + 64);
    }
    const f16* ks = smem + (i & 1) * 8192 + kh * 4096;
    const f16* vs = smem + 16384 + (i & 1) * 8192 + kh * 4096;

    // S^T = K @ Q^T for both q-chunks (K-frags read once)
    f32x4 s[2][4];
#pragma unroll
    for (int kc = 0; kc < 4; ++kc) {
      const f16x8 kf0 = *(const f16x8*)(&ks[(kc * 16 + n16) * 64 + fs0]);
      const f16x8 kf1 = *(const f16x8*)(&ks[(kc * 16 + n16) * 64 + fs1]);
#pragma unroll
      for (int qc = 0; qc < 2; ++qc) {
        f32x4 sv = (f32x4){0.f, 0.f, 0.f, 0.f};
        sv = MFMA16(kf0, qf[qc][0], sv);
        sv = MFMA16(kf1, qf[qc][1], sv);
        s[qc][kc] = sv;
      }
    }

    // p = 2^s (log2e folded into Q); packed cvt; lsum via ones-MFMA
    f16x4 pa[2][4];
#pragma unroll
    for (int qc = 0; qc < 2; ++qc)
#pragma unroll
      for (int kc = 0; kc < 4; ++kc) {
        float p0 = __builtin_amdgcn_exp2f(s[qc][kc][0]);
        float p1 = __builtin_amdgcn_exp2f(s[qc][kc][1]);
        float p2 = __builtin_amdgcn_exp2f(s[qc][kc][2]);
        float p3 = __builtin_amdgcn_exp2f(s[qc][kc][3]);
        pa[qc][kc] = pk4(p0, p1, p2, p3);
      }
#pragma unroll
    for (int kc = 0; kc < 4; ++kc) {
      lacc[0] = MFMA16K(pa[0][kc], onesb, lacc[0]);
      lacc[1] = MFMA16K(pa[1][kc], onesb, lacc[1]);
    }

    // O += P @ V (V-frags read once, shared by both q-chunks)
#pragma unroll
    for (int kc = 0; kc < 4; ++kc)
#pragma unroll
      for (int dt = 0; dt < 4; ++dt) {
        const f16x4 vb = *(const f16x4*)(&vs[dt * 1024 + voff[kc]]);
        o[0][dt] = MFMA16K(pa[0][kc], vb, o[0][dt]);
        o[1][dt] = MFMA16K(pa[1][kc], vb, o[1][dt]);
      }
  }

  // combine key-half partials via LDS (smem reused; 4 qg x 64 lanes x 40 f32)
  __syncthreads();
  float* red = (float*)smem;
  if (kh == 1) {
    float* p = red + ((size_t)(qg * 64 + lane)) * 40;
#pragma unroll
    for (int qc = 0; qc < 2; ++qc) {
#pragma unroll
      for (int dt = 0; dt < 4; ++dt)
        *(f32x4*)(p + (qc * 4 + dt) * 4) = o[qc][dt];
      *(f32x4*)(p + 32 + qc * 4) = lacc[qc];
    }
  }
  __syncthreads();
  if (kh == 0) {
    const float* p = red + ((size_t)(qg * 64 + lane)) * 40;
#pragma unroll
    for (int qc = 0; qc < 2; ++qc) {
#pragma unroll
      for (int dt = 0; dt < 4; ++dt) {
        f32x4 v = *(const f32x4*)(p + (qc * 4 + dt) * 4);
#pragma unroll
        for (int r = 0; r < 4; ++r) o[qc][dt][r] += v[r];
      }
      f32x4 lv = *(const f32x4*)(p + 32 + qc * 4);
#pragma unroll
      for (int r = 0; r < 4; ++r) lacc[qc][r] += lv[r];
    }

#pragma unroll
    for (int qc = 0; qc < 2; ++qc)
#pragma unroll
      for (int r = 0; r < 4; ++r) {
        float inv = 1.0f / lacc[qc][r];
        int nrow = qb + qg * 32 + qc * 16 + quad * 4 + r;
        f16* aop = AO + ((size_t)(b * N_ + nrow)) * H_ + h * 64;
#pragma unroll
        for (int dt = 0; dt < 4; ++dt)
          aop[dt * 16 + n16] = (f16)(o[qc][dt][r] * inv);
      }
  }
}

// ---------------------------------------------------------------------------
// Output GEMM, m97-style: out[4096,1024] = AO_f16 @ WoutT^T + bout (f32 out)
// ---------------------------------------------------------------------------
__global__ __launch_bounds__(256) void out_mfma(
    const f16* __restrict__ A, const f16* __restrict__ Wt,
    const float* __restrict__ bias, float* __restrict__ out) {
  const int bid = blockIdx.x;
  const int rb = (bid & 31) * 128;
  const int cb = (bid >> 5) * 128;
  const int t = threadIdx.x;
  const int lane = t & 63, wid = t >> 6;
  const int quad = lane >> 4, n16 = lane & 15;
  const int wm = wid >> 1, wn = wid & 1;

  __shared__ f16 As[128 * 32];
  __shared__ f16 Bs[128 * 32];

  f32x4 acc[4][4];
#pragma unroll
  for (int i = 0; i < 4; ++i)
#pragma unroll
    for (int j = 0; j < 4; ++j) acc[i][j] = (f32x4){0.f, 0.f, 0.f, 0.f};

  int srow0 = wid * 16 + (lane >> 2);
  int srow1 = 64 + srow0;
  int gl0 = ((lane & 3) ^ ((srow0 >> 1) & 3)) * 8;
  int gl1 = ((lane & 3) ^ ((srow1 >> 1) & 3)) * 8;
  const f16* gA0 = A + (size_t)(rb + srow0) * H_ + gl0;
  const f16* gA1 = A + (size_t)(rb + srow1) * H_ + gl1;
  const f16* gB0 = Wt + (size_t)(cb + srow0) * H_ + gl0;
  const f16* gB1 = Wt + (size_t)(cb + srow1) * H_ + gl1;
  f16* lA0 = &As[wid * 512];
  f16* lA1 = &As[2048 + wid * 512];
  f16* lB0 = &Bs[wid * 512];
  f16* lB1 = &Bs[2048 + wid * 512];

  const int fsw = (quad ^ ((n16 >> 1) & 3)) * 8;
  int aoff[4], boff[4];
#pragma unroll
  for (int i = 0; i < 4; ++i) {
    aoff[i] = (wm * 64 + i * 16 + n16) * 32 + fsw;
    boff[i] = (wn * 64 + i * 16 + n16) * 32 + fsw;
  }

  for (int kt = 0; kt < H_; kt += 32) {
    __syncthreads();
    cp16(lA0, gA0); cp16(lA1, gA1);
    cp16(lB0, gB0); cp16(lB1, gB1);
    gA0 += 32; gA1 += 32; gB0 += 32; gB1 += 32;
    __syncthreads();

    f16x8 af[4], bf[4];
#pragma unroll
    for (int mt = 0; mt < 4; ++mt) af[mt] = *(const f16x8*)(&As[aoff[mt]]);
#pragma unroll
    for (int nt = 0; nt < 4; ++nt) bf[nt] = *(const f16x8*)(&Bs[boff[nt]]);
#pragma unroll
    for (int mt = 0; mt < 4; ++mt)
#pragma unroll
      for (int nt = 0; nt < 4; ++nt)
        acc[mt][nt] = MFMA16(af[mt], bf[nt], acc[mt][nt]);
  }

#pragma unroll
  for (int nt = 0; nt < 4; ++nt) {
    int gcol = cb + wn * 64 + nt * 16 + n16;
    float bv = bias[gcol];
#pragma unroll
    for (int mt = 0; mt < 4; ++mt)
#pragma unroll
      for (int r = 0; r < 4; ++r) {
        int grow = rb + wm * 64 + mt * 16 + quad * 4 + r;
        out[(size_t)grow * H_ + gcol] = acc[mt][nt][r] + bv;
      }
  }
}

extern "C" void kernel_launch(void* const* d_in, const int* in_sizes, int n_in,
                              void* d_out, int out_size, void* d_ws, size_t ws_size,
                              hipStream_t stream) {
  const float* x    = (const float*)d_in[0];
  const float* x2   = (const float*)d_in[1];
  const float* Wqkv = (const float*)d_in[2];
  const float* Wout = (const float*)d_in[3];
  const float* bout = (const float*)d_in[4];
  float* out = (float*)d_out;

  const size_t per = (size_t)B_ * NH_ * N_ * D_;   // 4M f16 elements
  f16* Xc    = (f16*)d_ws;
  f16* X2c   = Xc + per;
  f16* Qw    = X2c + per;
  f16* Kw    = Qw + per;
  f16* Vtw   = Kw + per;
  f16* AO    = Vtw + per;
  f16* WqkvT = AO + per;                      // [3072][1024]
  f16* WoutT = WqkvT + (size_t)3072 * 1024;   // [1024][1024]

  prep<<<dim3(5120), 256, 0, stream>>>(x, x2, Xc, X2c, Wqkv, WqkvT, Wout, WoutT);
  qkv_mfma<<<dim3(768), 256, 0, stream>>>(Xc, X2c, WqkvT, Qw, Kw, Vtw);
  attn6<<<dim3(16, 32), 512, 0, stream>>>(Qw, Kw, Vtw, AO);
  out_mfma<<<dim3(256), 256, 0, stream>>>(AO, WoutT, bout, out);
}